// Round 4
// baseline (379.100 us; speedup 1.0000x reference)
//
#include <hip/hip_runtime.h>
#include <hip/hip_bf16.h>
#include <math.h>

#define BATCH 64
#define TLEN 512
#define DIM 768
#define NLAB 50

typedef __attribute__((ext_vector_type(8))) short short8;   // 8 bf16 (4 VGPRs)
typedef __attribute__((ext_vector_type(4))) float f32x4;    // MFMA acc

__device__ __forceinline__ unsigned short f2bf(float f) {
    unsigned int u = __float_as_uint(f);
    return (unsigned short)((u + 0x7FFFu + ((u >> 16) & 1u)) >> 16);
}

// ---------------------------------------------------------------------------
// prep: W fp32 [768 x 50] -> Bt bf16 [64 cols][768 k] (transposed, zero-pad)
// ---------------------------------------------------------------------------
__global__ __launch_bounds__(256) void wprep_kernel(const float* __restrict__ W,
                                                    unsigned short* __restrict__ Bt) {
    int idx = blockIdx.x * 256 + threadIdx.x;
    if (idx < 64 * DIM) {
        int c = idx / DIM;
        int k = idx - c * DIM;
        float v = (c < NLAB) ? W[k * NLAB + c] : 0.f;
        Bt[idx] = f2bf(v);
    }
}

// ---------------------------------------------------------------------------
// GEMM via MFMA bf16, direct-from-global (no LDS), deep K-unroll for MLP.
// Wave: 16 rows x 64 cols (4 n-tiles). K chunks of 32, unroll 8.
// ---------------------------------------------------------------------------
__global__ __launch_bounds__(256) void gemm_kernel(const float* __restrict__ A,
                                                   const unsigned short* __restrict__ Bt,
                                                   const float* __restrict__ bias,
                                                   float* __restrict__ out) {
    const int wave = threadIdx.x >> 6;
    const int lane = threadIdx.x & 63;
    const int m = lane & 15;
    const int quad = lane >> 4;
    const int row0 = blockIdx.x * 64 + wave * 16;

    f32x4 acc0 = {0.f, 0.f, 0.f, 0.f};
    f32x4 acc1 = {0.f, 0.f, 0.f, 0.f};
    f32x4 acc2 = {0.f, 0.f, 0.f, 0.f};
    f32x4 acc3 = {0.f, 0.f, 0.f, 0.f};

    const float* arow = A + (size_t)(row0 + m) * DIM + quad * 8;
    const unsigned short* b0 = Bt + (size_t)(0 * 16 + m) * DIM + quad * 8;
    const unsigned short* b1 = Bt + (size_t)(1 * 16 + m) * DIM + quad * 8;
    const unsigned short* b2 = Bt + (size_t)(2 * 16 + m) * DIM + quad * 8;
    const unsigned short* b3 = Bt + (size_t)(3 * 16 + m) * DIM + quad * 8;

#pragma unroll 8
    for (int k0 = 0; k0 < DIM; k0 += 32) {
        const float4 x = *(const float4*)(arow + k0);
        const float4 y = *(const float4*)(arow + k0 + 4);
        const short8 bf0 = *(const short8*)(b0 + k0);
        const short8 bf1 = *(const short8*)(b1 + k0);
        const short8 bf2 = *(const short8*)(b2 + k0);
        const short8 bf3 = *(const short8*)(b3 + k0);

        short8 af;
        af[0] = (short)f2bf(x.x); af[1] = (short)f2bf(x.y);
        af[2] = (short)f2bf(x.z); af[3] = (short)f2bf(x.w);
        af[4] = (short)f2bf(y.x); af[5] = (short)f2bf(y.y);
        af[6] = (short)f2bf(y.z); af[7] = (short)f2bf(y.w);

        acc0 = __builtin_amdgcn_mfma_f32_16x16x32_bf16(af, bf0, acc0, 0, 0, 0);
        acc1 = __builtin_amdgcn_mfma_f32_16x16x32_bf16(af, bf1, acc1, 0, 0, 0);
        acc2 = __builtin_amdgcn_mfma_f32_16x16x32_bf16(af, bf2, acc2, 0, 0, 0);
        acc3 = __builtin_amdgcn_mfma_f32_16x16x32_bf16(af, bf3, acc3, 0, 0, 0);
    }

    const f32x4 av[4] = {acc0, acc1, acc2, acc3};
#pragma unroll
    for (int nt = 0; nt < 4; ++nt) {
        const int col = nt * 16 + m;
        if (col < NLAB) {
            const float bv = bias[col];
#pragma unroll
            for (int r = 0; r < 4; ++r) {
                const int row = row0 + quad * 4 + r;
                out[(size_t)row * NLAB + col] = av[nt][r] + bv;
            }
        }
    }
}

// ---------------------------------------------------------------------------
// CRF: one wave per batch, lane j owns label j.
//   e_j = exp(alpha_j - A); per step: s = dot(e, expT[:,j]) via LDS broadcast,
//   u = s * exp(em) * rcp(e0_prev), A += log(e0_prev).
// v4: emission BLOCK prefetch (8 independent regs, consumed one full group
//     after issue -> no per-step vmcnt stall), double-buffered ea
//     (1 barrier/step), ea0 taken from first float4 (one less ds_read).
// ---------------------------------------------------------------------------
__device__ __forceinline__ float wave_sum(float v) {
#pragma unroll
    for (int off = 32; off > 0; off >>= 1) v += __shfl_xor(v, off, 64);
    return v;
}

__global__ __launch_bounds__(64) void crf_kernel(
    const float* __restrict__ logits,
    const int* __restrict__ labels,
    const void* __restrict__ maskp,
    const float* __restrict__ startT,
    const float* __restrict__ endT,
    const float* __restrict__ trans,
    float* __restrict__ llh) {
    const int b = blockIdx.x;
    const int lane = threadIdx.x;
    __shared__ __align__(16) float ea[2][64];

    // --- mask length (contiguous valid prefix) ---
    const int probe = ((const int*)maskp)[0];
    int len = 0;
    if (probe == 1) {
        const int* mk = (const int*)maskp + b * TLEN;
#pragma unroll
        for (int it = 0; it < 8; ++it)
            len += (int)__popcll(__ballot(mk[lane + it * 64] != 0));
    } else if (probe == 0x01010101) {
        const unsigned char* mk = (const unsigned char*)maskp + b * TLEN;
#pragma unroll
        for (int it = 0; it < 8; ++it)
            len += (int)__popcll(__ballot(mk[lane + it * 64] != 0));
    } else if (probe == 0x3F803F80) {
        const unsigned short* mk = (const unsigned short*)maskp + b * TLEN;
#pragma unroll
        for (int it = 0; it < 8; ++it)
            len += (int)__popcll(__ballot(mk[lane + it * 64] != 0));
    } else {
        const float* mk = (const float*)maskp + b * TLEN;
#pragma unroll
        for (int it = 0; it < 8; ++it)
            len += (int)__popcll(__ballot(mk[lane + it * 64] != 0.f));
    }

    const int j = lane;
    const int jc = (j < NLAB) ? j : (NLAB - 1);

    float et[52];
#pragma unroll
    for (int i = 0; i < 52; ++i) et[i] = 0.f;
    if (j < NLAB) {
        for (int i = 0; i < NLAB; ++i) et[i] = __expf(trans[i * NLAB + j]);
    }

    const float* em = logits + (size_t)b * TLEN * NLAB;

    float a0 = (j < NLAB) ? (startT[j] + em[j]) : 0.f;
    const float Abc = __shfl(a0, 0, 64);
    float e = (j < NLAB) ? __expf(a0 - Abc) : 0.f;
    float A = Abc;

    ea[0][lane] = e;
    __syncthreads();

    // emission block prefetch: emq holds em for t = tb .. tb+7 (len >= 256)
    float emq[8];
#pragma unroll
    for (int i = 0; i < 8; ++i) emq[i] = em[(1 + i) * NLAB + jc];

    int buf = 0;
    for (int tb = 1; tb < len; tb += 8) {
        // issue next group's 8 independent loads (consumed ~8 steps later)
        float nq[8];
#pragma unroll
        for (int i = 0; i < 8; ++i) {
            int tf = tb + 8 + i;
            tf = (tf < len) ? tf : (len - 1);
            nq[i] = em[tf * NLAB + jc];
        }

#pragma unroll
        for (int i = 0; i < 8; ++i) {
            const int t = tb + i;
            if (t < len) {                         // wave-uniform
                const float p = __expf(emq[i]);    // overlaps ds_read latency
                const float* eb = ea[buf];
                float sa, sb, sc, sd;
                float ea0;
                {
                    const float4 v = *(const float4*)&eb[0];
                    ea0 = v.x;
                    sa = v.x * et[0];
                    sb = v.y * et[1];
                    sc = v.z * et[2];
                    sd = v.w * et[3];
                }
#pragma unroll
                for (int qq = 1; qq < 13; ++qq) {
                    const float4 v = *(const float4*)&eb[qq * 4];
                    sa = fmaf(v.x, et[qq * 4 + 0], sa);
                    sb = fmaf(v.y, et[qq * 4 + 1], sb);
                    sc = fmaf(v.z, et[qq * 4 + 2], sc);
                    sd = fmaf(v.w, et[qq * 4 + 3], sd);
                }
                const float s = (sa + sb) + (sc + sd);
                const float r = __builtin_amdgcn_rcpf(ea0);
                const float u = s * (p * r);
                A += __logf(ea0);

                ea[buf ^ 1][lane] = u;
                __syncthreads();
                buf ^= 1;
                e = u;
            }
        }
#pragma unroll
        for (int i = 0; i < 8; ++i) emq[i] = nq[i];
    }

    const float wv = (j < NLAB) ? (e * __expf(endT[j])) : 0.f;
    const float den = A + __logf(wave_sum(wv));

    // numerator: gold path (contiguous mask -> parallel over t)
    const int* tg = labels + b * TLEN;
    float num = 0.f;
#pragma unroll
    for (int it = 0; it < 8; ++it) {
        const int t = lane + it * 64;
        if (t < len) {
            const int tag = tg[t];
            num += em[t * NLAB + tag];
            if (t >= 1) num += trans[tg[t - 1] * NLAB + tag];
        }
    }
    num = wave_sum(num);
    if (lane == 0) {
        num += startT[tg[0]] + endT[tg[len - 1]];
        llh[b] = num - den;
    }
}

__global__ __launch_bounds__(64) void loss_kernel(const float* __restrict__ llh,
                                                  float* __restrict__ out0) {
    float v = llh[threadIdx.x];
    v = wave_sum(v);
    if (threadIdx.x == 0) out0[0] = -(v * (1.0f / BATCH));
}

extern "C" void kernel_launch(void* const* d_in, const int* in_sizes, int n_in,
                              void* d_out, int out_size, void* d_ws, size_t ws_size,
                              hipStream_t stream) {
    (void)in_sizes; (void)n_in; (void)out_size; (void)ws_size;
    const float* emb    = (const float*)d_in[0];
    const int*   labels = (const int*)d_in[1];
    const void*  mask   = d_in[2];
    const float* W      = (const float*)d_in[3];
    const float* bias   = (const float*)d_in[4];
    const float* startT = (const float*)d_in[5];
    const float* endT   = (const float*)d_in[6];
    const float* trans  = (const float*)d_in[7];

    float* out    = (float*)d_out;
    float* logits = out + 1;
    float* llh    = (float*)d_ws;
    unsigned short* Bt = (unsigned short*)((char*)d_ws + 512);  // 96 KiB bf16 W^T

    wprep_kernel<<<(64 * DIM + 255) / 256, 256, 0, stream>>>(W, Bt);
    gemm_kernel<<<(BATCH * TLEN) / 64, 256, 0, stream>>>(emb, Bt, bias, logits);
    crf_kernel<<<BATCH, 64, 0, stream>>>(logits, labels, mask, startT, endT, trans, llh);
    loss_kernel<<<1, 64, 0, stream>>>(llh, out);
}

// Round 5
// 370.747 us; speedup vs baseline: 1.0225x; 1.0225x over previous
//
#include <hip/hip_runtime.h>
#include <hip/hip_bf16.h>
#include <math.h>

#define BATCH 64
#define TLEN 512
#define DIM 768
#define NLAB 50

typedef __attribute__((ext_vector_type(8))) short short8;   // 8 bf16 (4 VGPRs)
typedef __attribute__((ext_vector_type(4))) float f32x4;    // MFMA acc

__device__ __forceinline__ unsigned short f2bf(float f) {
    unsigned int u = __float_as_uint(f);
    return (unsigned short)((u + 0x7FFFu + ((u >> 16) & 1u)) >> 16);
}

// single-wave "barrier": DS ops drain (in-order) + compiler scheduling fence.
// Valid ONLY for 64-thread (one-wave) blocks: lanes share one PC, so the only
// hazard is LDS write->read visibility, which lgkmcnt(0) guarantees.
// Crucially does NOT drain vmcnt -> global prefetches stay in flight.
__device__ __forceinline__ void wave_lds_fence() {
    __asm__ __volatile__("s_waitcnt lgkmcnt(0)" ::: "memory");
    __builtin_amdgcn_wave_barrier();
}

// ---------------------------------------------------------------------------
// prep: W fp32 [768 x 50] -> Bt bf16 [64 cols][768 k] (transposed, zero-pad)
// ---------------------------------------------------------------------------
__global__ __launch_bounds__(256) void wprep_kernel(const float* __restrict__ W,
                                                    unsigned short* __restrict__ Bt) {
    int idx = blockIdx.x * 256 + threadIdx.x;
    if (idx < 64 * DIM) {
        int c = idx / DIM;
        int k = idx - c * DIM;
        float v = (c < NLAB) ? W[k * NLAB + c] : 0.f;
        Bt[idx] = f2bf(v);
    }
}

// ---------------------------------------------------------------------------
// GEMM: 256 thr / 4 waves, tile 128 rows x 64 cols, K chunks of 32.
// A staged COALESCED into LDS as fp32 (stride 36), B chunk staged bf16
// (stride 40). Double-buffered; loads issued before compute each chunk.
// Wave w computes rows w*32..w*32+31 (2 m-tiles) x 4 n-tiles = 8 MFMA/chunk.
// ---------------------------------------------------------------------------
#define AST 36
#define BSTC 40

__global__ __launch_bounds__(256, 1) void gemm_kernel(
    const float* __restrict__ A,              // [32768 x 768] fp32
    const unsigned short* __restrict__ Bt,    // [64 x 768] bf16 (W^T, padded)
    const float* __restrict__ bias,
    float* __restrict__ out)                  // [32768 x 50]
{
    __shared__ float As[2][128 * AST];        // 36864 B
    __shared__ short Bs[2][64 * BSTC];        // 10240 B

    const int tid = threadIdx.x;
    const int wave = tid >> 6;
    const int lane = tid & 63;
    const int m = lane & 15;
    const int q = lane >> 4;
    const int row0 = blockIdx.x * 128;

    // staging coords: A: u = tid + it*256 -> row u>>3 (0..127), float4 col u&7
    const int sr = tid >> 3;                  // base row for it=0 is u>>3
    (void)sr;
    // B: u = tid -> col u>>2 (0..63), short8 slot u&3

    f32x4 acc[2][4];
#pragma unroll
    for (int i = 0; i < 2; ++i)
#pragma unroll
        for (int j = 0; j < 4; ++j) acc[i][j] = (f32x4){0.f, 0.f, 0.f, 0.f};

    // ---- stage chunk 0 directly ----
#pragma unroll
    for (int it = 0; it < 4; ++it) {
        const int u = tid + it * 256;
        const int r = u >> 3, c = u & 7;
        const float4 v = *(const float4*)(A + (size_t)(row0 + r) * DIM + c * 4);
        *(float4*)&As[0][r * AST + c * 4] = v;
    }
    {
        const int col = tid >> 2, kk = (tid & 3) * 8;
        const short8 v = *(const short8*)(Bt + (size_t)col * DIM + kk);
        *(short8*)&Bs[0][col * BSTC + kk] = v;
    }
    __syncthreads();

    int buf = 0;
    for (int ch = 0; ch < DIM / 32; ++ch) {
        const int k0n = (ch + 1) * 32;
        float4 pa[4];
        short8 pb;
        if (ch < DIM / 32 - 1) {
#pragma unroll
            for (int it = 0; it < 4; ++it) {
                const int u = tid + it * 256;
                const int r = u >> 3, c = u & 7;
                pa[it] = *(const float4*)(A + (size_t)(row0 + r) * DIM + k0n + c * 4);
            }
            const int col = tid >> 2, kk = (tid & 3) * 8;
            pb = *(const short8*)(Bt + (size_t)col * DIM + k0n + kk);
        }

        // B frags (shared across both m-tiles)
        short8 bf[4];
#pragma unroll
        for (int nt = 0; nt < 4; ++nt)
            bf[nt] = *(const short8*)&Bs[buf][(nt * 16 + m) * BSTC + q * 8];

#pragma unroll
        for (int mt = 0; mt < 2; ++mt) {
            const int rr = wave * 32 + mt * 16 + m;
            const float4 xa = *(const float4*)&As[buf][rr * AST + q * 8];
            const float4 xb = *(const float4*)&As[buf][rr * AST + q * 8 + 4];
            short8 af;
            af[0] = (short)f2bf(xa.x); af[1] = (short)f2bf(xa.y);
            af[2] = (short)f2bf(xa.z); af[3] = (short)f2bf(xa.w);
            af[4] = (short)f2bf(xb.x); af[5] = (short)f2bf(xb.y);
            af[6] = (short)f2bf(xb.z); af[7] = (short)f2bf(xb.w);
            acc[mt][0] = __builtin_amdgcn_mfma_f32_16x16x32_bf16(af, bf[0], acc[mt][0], 0, 0, 0);
            acc[mt][1] = __builtin_amdgcn_mfma_f32_16x16x32_bf16(af, bf[1], acc[mt][1], 0, 0, 0);
            acc[mt][2] = __builtin_amdgcn_mfma_f32_16x16x32_bf16(af, bf[2], acc[mt][2], 0, 0, 0);
            acc[mt][3] = __builtin_amdgcn_mfma_f32_16x16x32_bf16(af, bf[3], acc[mt][3], 0, 0, 0);
        }

        if (ch < DIM / 32 - 1) {
            const int nb = buf ^ 1;
#pragma unroll
            for (int it = 0; it < 4; ++it) {
                const int u = tid + it * 256;
                const int r = u >> 3, c = u & 7;
                *(float4*)&As[nb][r * AST + c * 4] = pa[it];
            }
            const int col = tid >> 2, kk = (tid & 3) * 8;
            *(short8*)&Bs[nb][col * BSTC + kk] = pb;
        }
        __syncthreads();
        buf ^= 1;
    }

    // epilogue: row = row0 + wave*32 + mt*16 + q*4 + r, col = nt*16 + m
#pragma unroll
    for (int mt = 0; mt < 2; ++mt) {
#pragma unroll
        for (int nt = 0; nt < 4; ++nt) {
            const int col = nt * 16 + m;
            if (col < NLAB) {
                const float bv = bias[col];
#pragma unroll
                for (int r = 0; r < 4; ++r) {
                    const int row = row0 + wave * 32 + mt * 16 + q * 4 + r;
                    out[(size_t)row * NLAB + col] = acc[mt][nt][r] + bv;
                }
            }
        }
    }
}

// ---------------------------------------------------------------------------
// CRF: one wave per batch, lane j owns label j.
//   e_j = exp(alpha_j - A); per step: s = dot(e, expT[:,j]) via LDS broadcast,
//   u = s * exp(em) * rcp(e0_prev), A += log(e0_prev).
// v5: __syncthreads (which drains vmcnt(0) and defeated all prefetch) is
//     replaced by wave_lds_fence() -- legal for single-wave blocks. The
//     8-deep emission block prefetch now actually stays in flight.
// ---------------------------------------------------------------------------
__device__ __forceinline__ float wave_sum(float v) {
#pragma unroll
    for (int off = 32; off > 0; off >>= 1) v += __shfl_xor(v, off, 64);
    return v;
}

__global__ __launch_bounds__(64) void crf_kernel(
    const float* __restrict__ logits,
    const int* __restrict__ labels,
    const void* __restrict__ maskp,
    const float* __restrict__ startT,
    const float* __restrict__ endT,
    const float* __restrict__ trans,
    float* __restrict__ llh) {
    const int b = blockIdx.x;
    const int lane = threadIdx.x;
    __shared__ __align__(16) float ea[2][64];

    // --- mask length (contiguous valid prefix) ---
    const int probe = ((const int*)maskp)[0];
    int len = 0;
    if (probe == 1) {
        const int* mk = (const int*)maskp + b * TLEN;
#pragma unroll
        for (int it = 0; it < 8; ++it)
            len += (int)__popcll(__ballot(mk[lane + it * 64] != 0));
    } else if (probe == 0x01010101) {
        const unsigned char* mk = (const unsigned char*)maskp + b * TLEN;
#pragma unroll
        for (int it = 0; it < 8; ++it)
            len += (int)__popcll(__ballot(mk[lane + it * 64] != 0));
    } else if (probe == 0x3F803F80) {
        const unsigned short* mk = (const unsigned short*)maskp + b * TLEN;
#pragma unroll
        for (int it = 0; it < 8; ++it)
            len += (int)__popcll(__ballot(mk[lane + it * 64] != 0));
    } else {
        const float* mk = (const float*)maskp + b * TLEN;
#pragma unroll
        for (int it = 0; it < 8; ++it)
            len += (int)__popcll(__ballot(mk[lane + it * 64] != 0.f));
    }

    const int j = lane;
    const int jc = (j < NLAB) ? j : (NLAB - 1);

    float et[52];
#pragma unroll
    for (int i = 0; i < 52; ++i) et[i] = 0.f;
    if (j < NLAB) {
        for (int i = 0; i < NLAB; ++i) et[i] = __expf(trans[i * NLAB + j]);
    }

    const float* em = logits + (size_t)b * TLEN * NLAB;

    float a0 = (j < NLAB) ? (startT[j] + em[j]) : 0.f;
    const float Abc = __shfl(a0, 0, 64);
    float e = (j < NLAB) ? __expf(a0 - Abc) : 0.f;
    float A = Abc;

    ea[0][lane] = e;
    wave_lds_fence();

    // emission block prefetch: emq holds em for t = tb .. tb+7 (len >= 256)
    float emq[8];
#pragma unroll
    for (int i = 0; i < 8; ++i) emq[i] = em[(1 + i) * NLAB + jc];

    int buf = 0;
    for (int tb = 1; tb < len; tb += 8) {
        // issue next group's 8 independent loads (stay in flight all group)
        float nq[8];
#pragma unroll
        for (int i = 0; i < 8; ++i) {
            int tf = tb + 8 + i;
            tf = (tf < len) ? tf : (len - 1);
            nq[i] = em[tf * NLAB + jc];
        }

#pragma unroll
        for (int i = 0; i < 8; ++i) {
            const int t = tb + i;
            if (t < len) {                         // wave-uniform
                const float p = __expf(emq[i]);    // overlaps ds_read latency
                const float* eb = ea[buf];
                float sa, sb, sc, sd;
                float ea0;
                {
                    const float4 v = *(const float4*)&eb[0];
                    ea0 = v.x;
                    sa = v.x * et[0];
                    sb = v.y * et[1];
                    sc = v.z * et[2];
                    sd = v.w * et[3];
                }
#pragma unroll
                for (int qq = 1; qq < 13; ++qq) {
                    const float4 v = *(const float4*)&eb[qq * 4];
                    sa = fmaf(v.x, et[qq * 4 + 0], sa);
                    sb = fmaf(v.y, et[qq * 4 + 1], sb);
                    sc = fmaf(v.z, et[qq * 4 + 2], sc);
                    sd = fmaf(v.w, et[qq * 4 + 3], sd);
                }
                const float s = (sa + sb) + (sc + sd);
                const float r = __builtin_amdgcn_rcpf(ea0);
                const float u = s * (p * r);
                A += __logf(ea0);

                ea[buf ^ 1][lane] = u;
                wave_lds_fence();
                buf ^= 1;
                e = u;
            }
        }
#pragma unroll
        for (int i = 0; i < 8; ++i) emq[i] = nq[i];
    }

    const float wv = (j < NLAB) ? (e * __expf(endT[j])) : 0.f;
    const float den = A + __logf(wave_sum(wv));

    // numerator: gold path (contiguous mask -> parallel over t)
    const int* tg = labels + b * TLEN;
    float num = 0.f;
#pragma unroll
    for (int it = 0; it < 8; ++it) {
        const int t = lane + it * 64;
        if (t < len) {
            const int tag = tg[t];
            num += em[t * NLAB + tag];
            if (t >= 1) num += trans[tg[t - 1] * NLAB + tag];
        }
    }
    num = wave_sum(num);
    if (lane == 0) {
        num += startT[tg[0]] + endT[tg[len - 1]];
        llh[b] = num - den;
    }
}

__global__ __launch_bounds__(64) void loss_kernel(const float* __restrict__ llh,
                                                  float* __restrict__ out0) {
    float v = llh[threadIdx.x];
    v = wave_sum(v);
    if (threadIdx.x == 0) out0[0] = -(v * (1.0f / BATCH));
}

extern "C" void kernel_launch(void* const* d_in, const int* in_sizes, int n_in,
                              void* d_out, int out_size, void* d_ws, size_t ws_size,
                              hipStream_t stream) {
    (void)in_sizes; (void)n_in; (void)out_size; (void)ws_size;
    const float* emb    = (const float*)d_in[0];
    const int*   labels = (const int*)d_in[1];
    const void*  mask   = d_in[2];
    const float* W      = (const float*)d_in[3];
    const float* bias   = (const float*)d_in[4];
    const float* startT = (const float*)d_in[5];
    const float* endT   = (const float*)d_in[6];
    const float* trans  = (const float*)d_in[7];

    float* out    = (float*)d_out;
    float* logits = out + 1;
    float* llh    = (float*)d_ws;
    unsigned short* Bt = (unsigned short*)((char*)d_ws + 512);  // 96 KiB bf16 W^T

    wprep_kernel<<<(64 * DIM + 255) / 256, 256, 0, stream>>>(W, Bt);
    gemm_kernel<<<(BATCH * TLEN) / 128, 256, 0, stream>>>(emb, Bt, bias, logits);
    crf_kernel<<<BATCH, 64, 0, stream>>>(logits, labels, mask, startT, endT, trans, llh);
    loss_kernel<<<1, 64, 0, stream>>>(llh, out);
}

// Round 6
// 353.994 us; speedup vs baseline: 1.0709x; 1.0473x over previous
//
#include <hip/hip_runtime.h>
#include <hip/hip_bf16.h>
#include <math.h>

#define BATCH 64
#define TLEN 512
#define DIM 768
#define NLAB 50

typedef __attribute__((ext_vector_type(8))) short short8;   // 8 bf16 (4 VGPRs)
typedef __attribute__((ext_vector_type(4))) float f32x4;    // MFMA acc

__device__ __forceinline__ unsigned short f2bf(float f) {
    unsigned int u = __float_as_uint(f);
    return (unsigned short)((u + 0x7FFFu + ((u >> 16) & 1u)) >> 16);
}

// single-wave LDS fence: legal ONLY for 64-thread (one-wave) blocks.
__device__ __forceinline__ void wave_lds_fence() {
    __asm__ __volatile__("s_waitcnt lgkmcnt(0)" ::: "memory");
    __builtin_amdgcn_wave_barrier();
}

__device__ __forceinline__ float readlane0(float v) {
    return __uint_as_float(__builtin_amdgcn_readlane(__float_as_uint(v), 0));
}

// ---------------------------------------------------------------------------
// prep: W fp32 [768 x 50] -> Bt bf16 [64 cols][768 k] (transposed, zero-pad)
// ---------------------------------------------------------------------------
__global__ __launch_bounds__(256) void wprep_kernel(const float* __restrict__ W,
                                                    unsigned short* __restrict__ Bt) {
    int idx = blockIdx.x * 256 + threadIdx.x;
    if (idx < 64 * DIM) {
        int c = idx / DIM;
        int k = idx - c * DIM;
        float v = (c < NLAB) ? W[k * NLAB + c] : 0.f;
        Bt[idx] = f2bf(v);
    }
}

// ---------------------------------------------------------------------------
// GEMM: 256 thr / 4 waves, tile 128 rows x 64 cols, K chunks of 32, dbuf LDS.
// All register arrays de-arrayed to named scalars (no scratch demotion).
// ---------------------------------------------------------------------------
#define AST 36
#define BSTC 40

__global__ __launch_bounds__(256, 1) void gemm_kernel(
    const float* __restrict__ A,              // [32768 x 768] fp32
    const unsigned short* __restrict__ Bt,    // [64 x 768] bf16 (W^T, padded)
    const float* __restrict__ bias,
    float* __restrict__ out)                  // [32768 x 50]
{
    __shared__ float As[2][128 * AST];        // 36864 B
    __shared__ short Bs[2][64 * BSTC];        // 10240 B

    const int tid = threadIdx.x;
    const int wave = tid >> 6;
    const int lane = tid & 63;
    const int m = lane & 15;
    const int q = lane >> 4;
    const int row0 = blockIdx.x * 128;

    const int r0s = tid >> 3, c0s = tid & 7;          // A staging coords (it=0)
    const int bcol = tid >> 2, bkk = (tid & 3) * 8;   // B staging coords

    f32x4 acc00 = {0.f,0.f,0.f,0.f}, acc01 = {0.f,0.f,0.f,0.f};
    f32x4 acc02 = {0.f,0.f,0.f,0.f}, acc03 = {0.f,0.f,0.f,0.f};
    f32x4 acc10 = {0.f,0.f,0.f,0.f}, acc11 = {0.f,0.f,0.f,0.f};
    f32x4 acc12 = {0.f,0.f,0.f,0.f}, acc13 = {0.f,0.f,0.f,0.f};

    // ---- stage chunk 0 directly ----
    {
        *(float4*)&As[0][(r0s +  0) * AST + c0s * 4] = *(const float4*)(A + (size_t)(row0 + r0s +  0) * DIM + c0s * 4);
        *(float4*)&As[0][(r0s + 32) * AST + c0s * 4] = *(const float4*)(A + (size_t)(row0 + r0s + 32) * DIM + c0s * 4);
        *(float4*)&As[0][(r0s + 64) * AST + c0s * 4] = *(const float4*)(A + (size_t)(row0 + r0s + 64) * DIM + c0s * 4);
        *(float4*)&As[0][(r0s + 96) * AST + c0s * 4] = *(const float4*)(A + (size_t)(row0 + r0s + 96) * DIM + c0s * 4);
        *(short8*)&Bs[0][bcol * BSTC + bkk] = *(const short8*)(Bt + (size_t)bcol * DIM + bkk);
    }
    __syncthreads();

    int buf = 0;
    for (int ch = 0; ch < DIM / 32; ++ch) {
        const int k0n = (ch + 1) * 32;
        const bool havenext = (ch < DIM / 32 - 1);
        float4 pa0, pa1, pa2, pa3;
        short8 pb;
        if (havenext) {
            pa0 = *(const float4*)(A + (size_t)(row0 + r0s +  0) * DIM + k0n + c0s * 4);
            pa1 = *(const float4*)(A + (size_t)(row0 + r0s + 32) * DIM + k0n + c0s * 4);
            pa2 = *(const float4*)(A + (size_t)(row0 + r0s + 64) * DIM + k0n + c0s * 4);
            pa3 = *(const float4*)(A + (size_t)(row0 + r0s + 96) * DIM + k0n + c0s * 4);
            pb  = *(const short8*)(Bt + (size_t)bcol * DIM + k0n + bkk);
        }

        const short8 bq0 = *(const short8*)&Bs[buf][( 0 + m) * BSTC + q * 8];
        const short8 bq1 = *(const short8*)&Bs[buf][(16 + m) * BSTC + q * 8];
        const short8 bq2 = *(const short8*)&Bs[buf][(32 + m) * BSTC + q * 8];
        const short8 bq3 = *(const short8*)&Bs[buf][(48 + m) * BSTC + q * 8];

        {   // m-tile 0
            const int rr = wave * 32 + m;
            const float4 xa = *(const float4*)&As[buf][rr * AST + q * 8];
            const float4 xb = *(const float4*)&As[buf][rr * AST + q * 8 + 4];
            short8 af;
            af[0] = (short)f2bf(xa.x); af[1] = (short)f2bf(xa.y);
            af[2] = (short)f2bf(xa.z); af[3] = (short)f2bf(xa.w);
            af[4] = (short)f2bf(xb.x); af[5] = (short)f2bf(xb.y);
            af[6] = (short)f2bf(xb.z); af[7] = (short)f2bf(xb.w);
            acc00 = __builtin_amdgcn_mfma_f32_16x16x32_bf16(af, bq0, acc00, 0, 0, 0);
            acc01 = __builtin_amdgcn_mfma_f32_16x16x32_bf16(af, bq1, acc01, 0, 0, 0);
            acc02 = __builtin_amdgcn_mfma_f32_16x16x32_bf16(af, bq2, acc02, 0, 0, 0);
            acc03 = __builtin_amdgcn_mfma_f32_16x16x32_bf16(af, bq3, acc03, 0, 0, 0);
        }
        {   // m-tile 1
            const int rr = wave * 32 + 16 + m;
            const float4 xa = *(const float4*)&As[buf][rr * AST + q * 8];
            const float4 xb = *(const float4*)&As[buf][rr * AST + q * 8 + 4];
            short8 af;
            af[0] = (short)f2bf(xa.x); af[1] = (short)f2bf(xa.y);
            af[2] = (short)f2bf(xa.z); af[3] = (short)f2bf(xa.w);
            af[4] = (short)f2bf(xb.x); af[5] = (short)f2bf(xb.y);
            af[6] = (short)f2bf(xb.z); af[7] = (short)f2bf(xb.w);
            acc10 = __builtin_amdgcn_mfma_f32_16x16x32_bf16(af, bq0, acc10, 0, 0, 0);
            acc11 = __builtin_amdgcn_mfma_f32_16x16x32_bf16(af, bq1, acc11, 0, 0, 0);
            acc12 = __builtin_amdgcn_mfma_f32_16x16x32_bf16(af, bq2, acc12, 0, 0, 0);
            acc13 = __builtin_amdgcn_mfma_f32_16x16x32_bf16(af, bq3, acc13, 0, 0, 0);
        }

        if (havenext) {
            const int nb = buf ^ 1;
            *(float4*)&As[nb][(r0s +  0) * AST + c0s * 4] = pa0;
            *(float4*)&As[nb][(r0s + 32) * AST + c0s * 4] = pa1;
            *(float4*)&As[nb][(r0s + 64) * AST + c0s * 4] = pa2;
            *(float4*)&As[nb][(r0s + 96) * AST + c0s * 4] = pa3;
            *(short8*)&Bs[nb][bcol * BSTC + bkk] = pb;
        }
        __syncthreads();
        buf ^= 1;
    }

    // epilogue: row = row0 + wave*32 + mt*16 + q*4 + r, col = nt*16 + m
#pragma unroll
    for (int mt = 0; mt < 2; ++mt) {
        const f32x4 a0 = mt ? acc10 : acc00;
        const f32x4 a1 = mt ? acc11 : acc01;
        const f32x4 a2 = mt ? acc12 : acc02;
        const f32x4 a3 = mt ? acc13 : acc03;
        const int rb = row0 + wave * 32 + mt * 16 + q * 4;
#pragma unroll
        for (int nt = 0; nt < 4; ++nt) {
            const f32x4 av = (nt == 0) ? a0 : (nt == 1) ? a1 : (nt == 2) ? a2 : a3;
            const int col = nt * 16 + m;
            if (col < NLAB) {
                const float bv = bias[col];
#pragma unroll
                for (int r = 0; r < 4; ++r)
                    out[(size_t)(rb + r) * NLAB + col] = av[r] + bv;
            }
        }
    }
}

// ---------------------------------------------------------------------------
// CRF v6: et[] init fully unrolled (stays in VGPRs — the R1-R5 versions
// spilled it to scratch: VGPR_Count 56 can't hold a 52-float array).
// Raw-value recurrence: LDS holds raw v; invariant alpha_j = A + log v_j.
//   u_j = s_j * p_j * rcp(v0_prev);  A += log(v0_prev)   (both off-chain,
//   v0_prev from last step's v_readlane — VALU, no DS op).
// Chain: fence -> 13x ds_read_b128 (broadcast) -> 4x13 FMA -> 1 mul -> write.
// ---------------------------------------------------------------------------
__device__ __forceinline__ float wave_sum(float v) {
#pragma unroll
    for (int off = 32; off > 0; off >>= 1) v += __shfl_xor(v, off, 64);
    return v;
}

__global__ __launch_bounds__(64) void crf_kernel(
    const float* __restrict__ logits,
    const int* __restrict__ labels,
    const void* __restrict__ maskp,
    const float* __restrict__ startT,
    const float* __restrict__ endT,
    const float* __restrict__ trans,
    float* __restrict__ llh) {
    const int b = blockIdx.x;
    const int lane = threadIdx.x;
    __shared__ __align__(16) float ea[2][64];

    // --- mask length (contiguous valid prefix) ---
    const int probe = ((const int*)maskp)[0];
    int len = 0;
    if (probe == 1) {
        const int* mk = (const int*)maskp + b * TLEN;
#pragma unroll
        for (int it = 0; it < 8; ++it)
            len += (int)__popcll(__ballot(mk[lane + it * 64] != 0));
    } else if (probe == 0x01010101) {
        const unsigned char* mk = (const unsigned char*)maskp + b * TLEN;
#pragma unroll
        for (int it = 0; it < 8; ++it)
            len += (int)__popcll(__ballot(mk[lane + it * 64] != 0));
    } else if (probe == 0x3F803F80) {
        const unsigned short* mk = (const unsigned short*)maskp + b * TLEN;
#pragma unroll
        for (int it = 0; it < 8; ++it)
            len += (int)__popcll(__ballot(mk[lane + it * 64] != 0));
    } else {
        const float* mk = (const float*)maskp + b * TLEN;
#pragma unroll
        for (int it = 0; it < 8; ++it)
            len += (int)__popcll(__ballot(mk[lane + it * 64] != 0.f));
    }

    const int j = lane;
    const int jc = (j < NLAB) ? j : (NLAB - 1);

    // et[i] = exp(trans[i][j]) — FULLY UNROLLED init so it stays in VGPRs
    float et[52];
#pragma unroll
    for (int i = 0; i < 52; ++i) et[i] = 0.f;
    if (j < NLAB) {
#pragma unroll
        for (int i = 0; i < NLAB; ++i) et[i] = __expf(trans[i * NLAB + j]);
    }

    const float* em = logits + (size_t)b * TLEN * NLAB;

    float a0 = (j < NLAB) ? (startT[j] + em[j]) : 0.f;
    const float Abc = __shfl(a0, 0, 64);
    float e = (j < NLAB) ? __expf(a0 - Abc) : 0.f;
    float A = Abc;
    float v0cur = 1.0f;   // lane-0 value of current buffer (exp(0) = 1)

    ea[0][lane] = e;
    wave_lds_fence();

    // emission block prefetch (8 independent regs per group)
    float emq[8];
#pragma unroll
    for (int i = 0; i < 8; ++i) emq[i] = em[(1 + i) * NLAB + jc];

    int buf = 0;
    for (int tb = 1; tb < len; tb += 8) {
        float nq[8];
#pragma unroll
        for (int i = 0; i < 8; ++i) {
            int tf = tb + 8 + i;
            tf = (tf < len) ? tf : (len - 1);
            nq[i] = em[tf * NLAB + jc];
        }

#pragma unroll
        for (int i = 0; i < 8; ++i) {
            const int t = tb + i;
            if (t < len) {                                 // wave-uniform
                const float rv = __builtin_amdgcn_rcpf(v0cur);   // off-chain
                A += __logf(v0cur);                              // off-chain
                const float pr = __expf(emq[i]) * rv;            // off-chain

                const float* eb = ea[buf];
                float sa, sb, sc, sd;
                {
                    const float4 v = *(const float4*)&eb[0];
                    sa = v.x * et[0];
                    sb = v.y * et[1];
                    sc = v.z * et[2];
                    sd = v.w * et[3];
                }
#pragma unroll
                for (int qq = 1; qq < 13; ++qq) {
                    const float4 v = *(const float4*)&eb[qq * 4];
                    sa = fmaf(v.x, et[qq * 4 + 0], sa);
                    sb = fmaf(v.y, et[qq * 4 + 1], sb);
                    sc = fmaf(v.z, et[qq * 4 + 2], sc);
                    sd = fmaf(v.w, et[qq * 4 + 3], sd);
                }
                const float s = (sa + sb) + (sc + sd);
                const float u = s * pr;                    // raw (un-normalized)

                ea[buf ^ 1][lane] = u;
                wave_lds_fence();
                v0cur = readlane0(u);                      // for next step
                buf ^= 1;
                e = u;
            }
        }
#pragma unroll
        for (int i = 0; i < 8; ++i) emq[i] = nq[i];
    }

    // den = A + log( sum_j v_j * exp(end_j) )   [alpha_j = A + log v_j]
    const float wv = (j < NLAB) ? (e * __expf(endT[j])) : 0.f;
    const float den = A + __logf(wave_sum(wv));

    // numerator: gold path (contiguous mask -> parallel over t)
    const int* tg = labels + b * TLEN;
    float num = 0.f;
#pragma unroll
    for (int it = 0; it < 8; ++it) {
        const int t = lane + it * 64;
        if (t < len) {
            const int tag = tg[t];
            num += em[t * NLAB + tag];
            if (t >= 1) num += trans[tg[t - 1] * NLAB + tag];
        }
    }
    num = wave_sum(num);
    if (lane == 0) {
        num += startT[tg[0]] + endT[tg[len - 1]];
        llh[b] = num - den;
    }
}

__global__ __launch_bounds__(64) void loss_kernel(const float* __restrict__ llh,
                                                  float* __restrict__ out0) {
    float v = llh[threadIdx.x];
    v = wave_sum(v);
    if (threadIdx.x == 0) out0[0] = -(v * (1.0f / BATCH));
}

extern "C" void kernel_launch(void* const* d_in, const int* in_sizes, int n_in,
                              void* d_out, int out_size, void* d_ws, size_t ws_size,
                              hipStream_t stream) {
    (void)in_sizes; (void)n_in; (void)out_size; (void)ws_size;
    const float* emb    = (const float*)d_in[0];
    const int*   labels = (const int*)d_in[1];
    const void*  mask   = d_in[2];
    const float* W      = (const float*)d_in[3];
    const float* bias   = (const float*)d_in[4];
    const float* startT = (const float*)d_in[5];
    const float* endT   = (const float*)d_in[6];
    const float* trans  = (const float*)d_in[7];

    float* out    = (float*)d_out;
    float* logits = out + 1;
    float* llh    = (float*)d_ws;
    unsigned short* Bt = (unsigned short*)((char*)d_ws + 512);  // 96 KiB bf16 W^T

    wprep_kernel<<<(64 * DIM + 255) / 256, 256, 0, stream>>>(W, Bt);
    gemm_kernel<<<(BATCH * TLEN) / 128, 256, 0, stream>>>(emb, Bt, bias, logits);
    crf_kernel<<<BATCH, 64, 0, stream>>>(logits, labels, mask, startT, endT, trans, llh);
    loss_kernel<<<1, 64, 0, stream>>>(llh, out);
}

// Round 7
// 341.668 us; speedup vs baseline: 1.1096x; 1.0361x over previous
//
#include <hip/hip_runtime.h>
#include <hip/hip_bf16.h>
#include <math.h>

#define BATCH 64
#define TLEN 512
#define DIM 768
#define NLAB 50

typedef __attribute__((ext_vector_type(8))) short short8;   // 8 bf16 (4 VGPRs)
typedef __attribute__((ext_vector_type(4))) float f32x4;    // MFMA acc

__device__ __forceinline__ unsigned short f2bf(float f) {
    unsigned int u = __float_as_uint(f);
    return (unsigned short)((u + 0x7FFFu + ((u >> 16) & 1u)) >> 16);
}

// single-wave LDS fence: legal ONLY for 64-thread (one-wave) blocks.
// Drains lgkm (DS) only -> global prefetches stay in flight.
__device__ __forceinline__ void wave_lds_fence() {
    __asm__ __volatile__("s_waitcnt lgkmcnt(0)" ::: "memory");
    __builtin_amdgcn_wave_barrier();
}

__device__ __forceinline__ float readlane0(float v) {
    return __uint_as_float(__builtin_amdgcn_readlane(__float_as_uint(v), 0));
}

// ---------------------------------------------------------------------------
// prep: W fp32 [768 x 50] -> Bt bf16 [64 cols][768 k] (transposed, zero-pad)
// ---------------------------------------------------------------------------
__global__ __launch_bounds__(256) void wprep_kernel(const float* __restrict__ W,
                                                    unsigned short* __restrict__ Bt) {
    int idx = blockIdx.x * 256 + threadIdx.x;
    if (idx < 64 * DIM) {
        int c = idx / DIM;
        int k = idx - c * DIM;
        float v = (c < NLAB) ? W[k * NLAB + c] : 0.f;
        Bt[idx] = f2bf(v);
    }
}

// ---------------------------------------------------------------------------
// GEMM: 256 thr / 4 waves, tile 128 rows x 64 cols, K chunks of 32, dbuf LDS.
// (unchanged from R6 -- control while crf is fixed)
// ---------------------------------------------------------------------------
#define AST 36
#define BSTC 40

__global__ __launch_bounds__(256, 1) void gemm_kernel(
    const float* __restrict__ A,              // [32768 x 768] fp32
    const unsigned short* __restrict__ Bt,    // [64 x 768] bf16 (W^T, padded)
    const float* __restrict__ bias,
    float* __restrict__ out)                  // [32768 x 50]
{
    __shared__ float As[2][128 * AST];
    __shared__ short Bs[2][64 * BSTC];

    const int tid = threadIdx.x;
    const int wave = tid >> 6;
    const int lane = tid & 63;
    const int m = lane & 15;
    const int q = lane >> 4;
    const int row0 = blockIdx.x * 128;

    const int r0s = tid >> 3, c0s = tid & 7;
    const int bcol = tid >> 2, bkk = (tid & 3) * 8;

    f32x4 acc00 = {0.f,0.f,0.f,0.f}, acc01 = {0.f,0.f,0.f,0.f};
    f32x4 acc02 = {0.f,0.f,0.f,0.f}, acc03 = {0.f,0.f,0.f,0.f};
    f32x4 acc10 = {0.f,0.f,0.f,0.f}, acc11 = {0.f,0.f,0.f,0.f};
    f32x4 acc12 = {0.f,0.f,0.f,0.f}, acc13 = {0.f,0.f,0.f,0.f};

    {
        *(float4*)&As[0][(r0s +  0) * AST + c0s * 4] = *(const float4*)(A + (size_t)(row0 + r0s +  0) * DIM + c0s * 4);
        *(float4*)&As[0][(r0s + 32) * AST + c0s * 4] = *(const float4*)(A + (size_t)(row0 + r0s + 32) * DIM + c0s * 4);
        *(float4*)&As[0][(r0s + 64) * AST + c0s * 4] = *(const float4*)(A + (size_t)(row0 + r0s + 64) * DIM + c0s * 4);
        *(float4*)&As[0][(r0s + 96) * AST + c0s * 4] = *(const float4*)(A + (size_t)(row0 + r0s + 96) * DIM + c0s * 4);
        *(short8*)&Bs[0][bcol * BSTC + bkk] = *(const short8*)(Bt + (size_t)bcol * DIM + bkk);
    }
    __syncthreads();

    int buf = 0;
    for (int ch = 0; ch < DIM / 32; ++ch) {
        const int k0n = (ch + 1) * 32;
        const bool havenext = (ch < DIM / 32 - 1);
        float4 pa0, pa1, pa2, pa3;
        short8 pb;
        if (havenext) {
            pa0 = *(const float4*)(A + (size_t)(row0 + r0s +  0) * DIM + k0n + c0s * 4);
            pa1 = *(const float4*)(A + (size_t)(row0 + r0s + 32) * DIM + k0n + c0s * 4);
            pa2 = *(const float4*)(A + (size_t)(row0 + r0s + 64) * DIM + k0n + c0s * 4);
            pa3 = *(const float4*)(A + (size_t)(row0 + r0s + 96) * DIM + k0n + c0s * 4);
            pb  = *(const short8*)(Bt + (size_t)bcol * DIM + k0n + bkk);
        }

        const short8 bq0 = *(const short8*)&Bs[buf][( 0 + m) * BSTC + q * 8];
        const short8 bq1 = *(const short8*)&Bs[buf][(16 + m) * BSTC + q * 8];
        const short8 bq2 = *(const short8*)&Bs[buf][(32 + m) * BSTC + q * 8];
        const short8 bq3 = *(const short8*)&Bs[buf][(48 + m) * BSTC + q * 8];

        {   // m-tile 0
            const int rr = wave * 32 + m;
            const float4 xa = *(const float4*)&As[buf][rr * AST + q * 8];
            const float4 xb = *(const float4*)&As[buf][rr * AST + q * 8 + 4];
            short8 af;
            af[0] = (short)f2bf(xa.x); af[1] = (short)f2bf(xa.y);
            af[2] = (short)f2bf(xa.z); af[3] = (short)f2bf(xa.w);
            af[4] = (short)f2bf(xb.x); af[5] = (short)f2bf(xb.y);
            af[6] = (short)f2bf(xb.z); af[7] = (short)f2bf(xb.w);
            acc00 = __builtin_amdgcn_mfma_f32_16x16x32_bf16(af, bq0, acc00, 0, 0, 0);
            acc01 = __builtin_amdgcn_mfma_f32_16x16x32_bf16(af, bq1, acc01, 0, 0, 0);
            acc02 = __builtin_amdgcn_mfma_f32_16x16x32_bf16(af, bq2, acc02, 0, 0, 0);
            acc03 = __builtin_amdgcn_mfma_f32_16x16x32_bf16(af, bq3, acc03, 0, 0, 0);
        }
        {   // m-tile 1
            const int rr = wave * 32 + 16 + m;
            const float4 xa = *(const float4*)&As[buf][rr * AST + q * 8];
            const float4 xb = *(const float4*)&As[buf][rr * AST + q * 8 + 4];
            short8 af;
            af[0] = (short)f2bf(xa.x); af[1] = (short)f2bf(xa.y);
            af[2] = (short)f2bf(xa.z); af[3] = (short)f2bf(xa.w);
            af[4] = (short)f2bf(xb.x); af[5] = (short)f2bf(xb.y);
            af[6] = (short)f2bf(xb.z); af[7] = (short)f2bf(xb.w);
            acc10 = __builtin_amdgcn_mfma_f32_16x16x32_bf16(af, bq0, acc10, 0, 0, 0);
            acc11 = __builtin_amdgcn_mfma_f32_16x16x32_bf16(af, bq1, acc11, 0, 0, 0);
            acc12 = __builtin_amdgcn_mfma_f32_16x16x32_bf16(af, bq2, acc12, 0, 0, 0);
            acc13 = __builtin_amdgcn_mfma_f32_16x16x32_bf16(af, bq3, acc13, 0, 0, 0);
        }

        if (havenext) {
            const int nb = buf ^ 1;
            *(float4*)&As[nb][(r0s +  0) * AST + c0s * 4] = pa0;
            *(float4*)&As[nb][(r0s + 32) * AST + c0s * 4] = pa1;
            *(float4*)&As[nb][(r0s + 64) * AST + c0s * 4] = pa2;
            *(float4*)&As[nb][(r0s + 96) * AST + c0s * 4] = pa3;
            *(short8*)&Bs[nb][bcol * BSTC + bkk] = pb;
        }
        __syncthreads();
        buf ^= 1;
    }

#pragma unroll
    for (int mt = 0; mt < 2; ++mt) {
        const f32x4 a0 = mt ? acc10 : acc00;
        const f32x4 a1 = mt ? acc11 : acc01;
        const f32x4 a2 = mt ? acc12 : acc02;
        const f32x4 a3 = mt ? acc13 : acc03;
        const int rb = row0 + wave * 32 + mt * 16 + q * 4;
#pragma unroll
        for (int nt = 0; nt < 4; ++nt) {
            const f32x4 av = (nt == 0) ? a0 : (nt == 1) ? a1 : (nt == 2) ? a2 : a3;
            const int col = nt * 16 + m;
            if (col < NLAB) {
                const float bv = bias[col];
#pragma unroll
                for (int r = 0; r < 4; ++r)
                    out[(size_t)(rb + r) * NLAB + col] = av[r] + bv;
            }
        }
    }
}

// ---------------------------------------------------------------------------
// CRF v7: ZERO local arrays. SROA runs before loop unrolling, so any local
// array indexed in a loop (et[52], emq[8]) lands in SCRATCH -> 13 buffer_loads
// on the critical path every step (VGPR_Count=60 proved it, R1-R6).
// et -> 13 named float4 (macro-initialized, constant indices).
// emission pipeline -> 4 named scalars rotated by assignment.
// ---------------------------------------------------------------------------
__device__ __forceinline__ float wave_sum(float v) {
#pragma unroll
    for (int off = 32; off > 0; off >>= 1) v += __shfl_xor(v, off, 64);
    return v;
}

#define ET_INIT(v, base)                            \
    v.x = __expf(trans[(base + 0) * NLAB + j]);     \
    v.y = __expf(trans[(base + 1) * NLAB + j]);     \
    v.z = __expf(trans[(base + 2) * NLAB + j]);     \
    v.w = __expf(trans[(base + 3) * NLAB + j]);

#define DOT4(idx, ee)                               \
    {                                               \
        const float4 v = *(const float4*)&eb[(idx) * 4]; \
        sa = fmaf(v.x, ee.x, sa);                   \
        sb = fmaf(v.y, ee.y, sb);                   \
        sc = fmaf(v.z, ee.z, sc);                   \
        sd = fmaf(v.w, ee.w, sd);                   \
    }

__global__ __launch_bounds__(64) void crf_kernel(
    const float* __restrict__ logits,
    const int* __restrict__ labels,
    const void* __restrict__ maskp,
    const float* __restrict__ startT,
    const float* __restrict__ endT,
    const float* __restrict__ trans,
    float* __restrict__ llh) {
    const int b = blockIdx.x;
    const int lane = threadIdx.x;
    __shared__ __align__(16) float ea[2][64];

    // --- mask length (contiguous valid prefix) ---
    const int probe = ((const int*)maskp)[0];
    int len = 0;
    if (probe == 1) {
        const int* mk = (const int*)maskp + b * TLEN;
#pragma unroll
        for (int it = 0; it < 8; ++it)
            len += (int)__popcll(__ballot(mk[lane + it * 64] != 0));
    } else if (probe == 0x01010101) {
        const unsigned char* mk = (const unsigned char*)maskp + b * TLEN;
#pragma unroll
        for (int it = 0; it < 8; ++it)
            len += (int)__popcll(__ballot(mk[lane + it * 64] != 0));
    } else if (probe == 0x3F803F80) {
        const unsigned short* mk = (const unsigned short*)maskp + b * TLEN;
#pragma unroll
        for (int it = 0; it < 8; ++it)
            len += (int)__popcll(__ballot(mk[lane + it * 64] != 0));
    } else {
        const float* mk = (const float*)maskp + b * TLEN;
#pragma unroll
        for (int it = 0; it < 8; ++it)
            len += (int)__popcll(__ballot(mk[lane + it * 64] != 0.f));
    }

    const int j = lane;
    const int jc = (j < NLAB) ? j : (NLAB - 1);

    // et = exp(trans[:, j]) in 13 named float4 registers
    float4 et0  = {0.f,0.f,0.f,0.f}, et1  = {0.f,0.f,0.f,0.f};
    float4 et2  = {0.f,0.f,0.f,0.f}, et3  = {0.f,0.f,0.f,0.f};
    float4 et4  = {0.f,0.f,0.f,0.f}, et5  = {0.f,0.f,0.f,0.f};
    float4 et6  = {0.f,0.f,0.f,0.f}, et7  = {0.f,0.f,0.f,0.f};
    float4 et8  = {0.f,0.f,0.f,0.f}, et9  = {0.f,0.f,0.f,0.f};
    float4 et10 = {0.f,0.f,0.f,0.f}, et11 = {0.f,0.f,0.f,0.f};
    float4 et12 = {0.f,0.f,0.f,0.f};
    if (j < NLAB) {
        ET_INIT(et0,  0)  ET_INIT(et1,  4)  ET_INIT(et2,  8)
        ET_INIT(et3,  12) ET_INIT(et4,  16) ET_INIT(et5,  20)
        ET_INIT(et6,  24) ET_INIT(et7,  28) ET_INIT(et8,  32)
        ET_INIT(et9,  36) ET_INIT(et10, 40) ET_INIT(et11, 44)
        et12.x = __expf(trans[48 * NLAB + j]);
        et12.y = __expf(trans[49 * NLAB + j]);
    }

    const float* em = logits + (size_t)b * TLEN * NLAB;

    float a0v = (j < NLAB) ? (startT[j] + em[j]) : 0.f;
    const float Abc = __shfl(a0v, 0, 64);
    float e = (j < NLAB) ? __expf(a0v - Abc) : 0.f;
    float A = Abc;
    float v0cur = 1.0f;   // lane-0 raw value of current buffer (exp(0)=1)

    ea[0][lane] = e;
    wave_lds_fence();

    // 4-deep emission pipeline: named scalars, rotated by assignment.
    // Invariant at loop top for step t: pcur = exp(em_t), q0..q3 = em_{t+1..t+4}
    float q0 = em[1 * NLAB + jc];
    float q1 = em[2 * NLAB + jc];
    float q2 = em[3 * NLAB + jc];
    float q3 = em[4 * NLAB + jc];
    float pcur = __expf(q0);
    q0 = q1; q1 = q2; q2 = q3; q3 = em[5 * NLAB + jc];

    int buf = 0;
    for (int t = 1; t < len; ++t) {
        int tf = t + 5; tf = (tf < len) ? tf : (len - 1);
        const float newem = em[tf * NLAB + jc];      // issued, used 4 iters later
        const float pnext = __expf(q0);              // off-chain
        const float rv = __builtin_amdgcn_rcpf(v0cur);   // off-chain
        A += __logf(v0cur);                              // off-chain
        const float pr = pcur * rv;                      // off-chain

        const float* eb = ea[buf];
        float sa = 0.f, sb = 0.f, sc = 0.f, sd = 0.f;
        DOT4(0, et0)   DOT4(1, et1)   DOT4(2, et2)   DOT4(3, et3)
        DOT4(4, et4)   DOT4(5, et5)   DOT4(6, et6)   DOT4(7, et7)
        DOT4(8, et8)   DOT4(9, et9)   DOT4(10, et10) DOT4(11, et11)
        DOT4(12, et12)
        const float s = (sa + sb) + (sc + sd);
        const float u = s * pr;                      // raw (un-normalized)

        ea[buf ^ 1][lane] = u;
        wave_lds_fence();
        v0cur = readlane0(u);
        buf ^= 1;
        e = u;
        pcur = pnext; q0 = q1; q1 = q2; q2 = q3; q3 = newem;
    }

    // den = A + log( sum_j v_j * exp(end_j) )   [alpha_j = A + log v_j]
    const float wv = (j < NLAB) ? (e * __expf(endT[j])) : 0.f;
    const float den = A + __logf(wave_sum(wv));

    // numerator: gold path (contiguous mask -> parallel over t)
    const int* tg = labels + b * TLEN;
    float num = 0.f;
#pragma unroll
    for (int it = 0; it < 8; ++it) {
        const int t = lane + it * 64;
        if (t < len) {
            const int tag = tg[t];
            num += em[t * NLAB + tag];
            if (t >= 1) num += trans[tg[t - 1] * NLAB + tag];
        }
    }
    num = wave_sum(num);
    if (lane == 0) {
        num += startT[tg[0]] + endT[tg[len - 1]];
        llh[b] = num - den;
    }
}

__global__ __launch_bounds__(64) void loss_kernel(const float* __restrict__ llh,
                                                  float* __restrict__ out0) {
    float v = llh[threadIdx.x];
    v = wave_sum(v);
    if (threadIdx.x == 0) out0[0] = -(v * (1.0f / BATCH));
}

extern "C" void kernel_launch(void* const* d_in, const int* in_sizes, int n_in,
                              void* d_out, int out_size, void* d_ws, size_t ws_size,
                              hipStream_t stream) {
    (void)in_sizes; (void)n_in; (void)out_size; (void)ws_size;
    const float* emb    = (const float*)d_in[0];
    const int*   labels = (const int*)d_in[1];
    const void*  mask   = d_in[2];
    const float* W      = (const float*)d_in[3];
    const float* bias   = (const float*)d_in[4];
    const float* startT = (const float*)d_in[5];
    const float* endT   = (const float*)d_in[6];
    const float* trans  = (const float*)d_in[7];

    float* out    = (float*)d_out;
    float* logits = out + 1;
    float* llh    = (float*)d_ws;
    unsigned short* Bt = (unsigned short*)((char*)d_ws + 512);  // 96 KiB bf16 W^T

    wprep_kernel<<<(64 * DIM + 255) / 256, 256, 0, stream>>>(W, Bt);
    gemm_kernel<<<(BATCH * TLEN) / 128, 256, 0, stream>>>(emb, Bt, bias, logits);
    crf_kernel<<<BATCH, 64, 0, stream>>>(logits, labels, mask, startT, endT, trans, llh);
    loss_kernel<<<1, 64, 0, stream>>>(llh, out);
}

// Round 8
// 323.539 us; speedup vs baseline: 1.1717x; 1.0560x over previous
//
#include <hip/hip_runtime.h>
#include <hip/hip_bf16.h>
#include <math.h>

#define BATCH 64
#define TLEN 512
#define DIM 768
#define NLAB 50

typedef __attribute__((ext_vector_type(8))) short short8;   // 8 bf16 (4 VGPRs)
typedef __attribute__((ext_vector_type(4))) float f32x4;    // MFMA acc

__device__ __forceinline__ unsigned short f2bf(float f) {
    unsigned int u = __float_as_uint(f);
    return (unsigned short)((u + 0x7FFFu + ((u >> 16) & 1u)) >> 16);
}

// single-wave LDS fence: legal ONLY for 64-thread (one-wave) blocks.
// Drains lgkm (DS) only -> global prefetches stay in flight.
__device__ __forceinline__ void wave_lds_fence() {
    __asm__ __volatile__("s_waitcnt lgkmcnt(0)" ::: "memory");
    __builtin_amdgcn_wave_barrier();
}

__device__ __forceinline__ float readlane0(float v) {
    return __uint_as_float(__builtin_amdgcn_readlane(__float_as_uint(v), 0));
}

// ---------------------------------------------------------------------------
// prep: W fp32 [768 x 50] -> Bt bf16 [64 cols][768 k] (transposed, zero-pad)
// ---------------------------------------------------------------------------
__global__ __launch_bounds__(256) void wprep_kernel(const float* __restrict__ W,
                                                    unsigned short* __restrict__ Bt) {
    int idx = blockIdx.x * 256 + threadIdx.x;
    if (idx < 64 * DIM) {
        int c = idx / DIM;
        int k = idx - c * DIM;
        float v = (c < NLAB) ? W[k * NLAB + c] : 0.f;
        Bt[idx] = f2bf(v);
    }
}

// ---------------------------------------------------------------------------
// GEMM: 256 thr / 4 waves, tile 128 rows x 64 cols, K chunks of 32, dbuf LDS.
// waves_per_eu(1,1): full VGPR budget (4 waves spread on 4 SIMDs anyway).
// ---------------------------------------------------------------------------
#define AST 36
#define BSTC 40

__global__ __launch_bounds__(256, 1) __attribute__((amdgpu_waves_per_eu(1, 1)))
void gemm_kernel(
    const float* __restrict__ A,              // [32768 x 768] fp32
    const unsigned short* __restrict__ Bt,    // [64 x 768] bf16 (W^T, padded)
    const float* __restrict__ bias,
    float* __restrict__ out)                  // [32768 x 50]
{
    __shared__ float As[2][128 * AST];
    __shared__ short Bs[2][64 * BSTC];

    const int tid = threadIdx.x;
    const int wave = tid >> 6;
    const int lane = tid & 63;
    const int m = lane & 15;
    const int q = lane >> 4;
    const int row0 = blockIdx.x * 128;

    const int r0s = tid >> 3, c0s = tid & 7;
    const int bcol = tid >> 2, bkk = (tid & 3) * 8;

    f32x4 acc00 = {0.f,0.f,0.f,0.f}, acc01 = {0.f,0.f,0.f,0.f};
    f32x4 acc02 = {0.f,0.f,0.f,0.f}, acc03 = {0.f,0.f,0.f,0.f};
    f32x4 acc10 = {0.f,0.f,0.f,0.f}, acc11 = {0.f,0.f,0.f,0.f};
    f32x4 acc12 = {0.f,0.f,0.f,0.f}, acc13 = {0.f,0.f,0.f,0.f};

    {
        *(float4*)&As[0][(r0s +  0) * AST + c0s * 4] = *(const float4*)(A + (size_t)(row0 + r0s +  0) * DIM + c0s * 4);
        *(float4*)&As[0][(r0s + 32) * AST + c0s * 4] = *(const float4*)(A + (size_t)(row0 + r0s + 32) * DIM + c0s * 4);
        *(float4*)&As[0][(r0s + 64) * AST + c0s * 4] = *(const float4*)(A + (size_t)(row0 + r0s + 64) * DIM + c0s * 4);
        *(float4*)&As[0][(r0s + 96) * AST + c0s * 4] = *(const float4*)(A + (size_t)(row0 + r0s + 96) * DIM + c0s * 4);
        *(short8*)&Bs[0][bcol * BSTC + bkk] = *(const short8*)(Bt + (size_t)bcol * DIM + bkk);
    }
    __syncthreads();

    int buf = 0;
    for (int ch = 0; ch < DIM / 32; ++ch) {
        const int k0n = (ch + 1) * 32;
        const bool havenext = (ch < DIM / 32 - 1);
        float4 pa0, pa1, pa2, pa3;
        short8 pb;
        if (havenext) {
            pa0 = *(const float4*)(A + (size_t)(row0 + r0s +  0) * DIM + k0n + c0s * 4);
            pa1 = *(const float4*)(A + (size_t)(row0 + r0s + 32) * DIM + k0n + c0s * 4);
            pa2 = *(const float4*)(A + (size_t)(row0 + r0s + 64) * DIM + k0n + c0s * 4);
            pa3 = *(const float4*)(A + (size_t)(row0 + r0s + 96) * DIM + k0n + c0s * 4);
            pb  = *(const short8*)(Bt + (size_t)bcol * DIM + k0n + bkk);
        }

        const short8 bq0 = *(const short8*)&Bs[buf][( 0 + m) * BSTC + q * 8];
        const short8 bq1 = *(const short8*)&Bs[buf][(16 + m) * BSTC + q * 8];
        const short8 bq2 = *(const short8*)&Bs[buf][(32 + m) * BSTC + q * 8];
        const short8 bq3 = *(const short8*)&Bs[buf][(48 + m) * BSTC + q * 8];

        {   // m-tile 0
            const int rr = wave * 32 + m;
            const float4 xa = *(const float4*)&As[buf][rr * AST + q * 8];
            const float4 xb = *(const float4*)&As[buf][rr * AST + q * 8 + 4];
            short8 af;
            af[0] = (short)f2bf(xa.x); af[1] = (short)f2bf(xa.y);
            af[2] = (short)f2bf(xa.z); af[3] = (short)f2bf(xa.w);
            af[4] = (short)f2bf(xb.x); af[5] = (short)f2bf(xb.y);
            af[6] = (short)f2bf(xb.z); af[7] = (short)f2bf(xb.w);
            acc00 = __builtin_amdgcn_mfma_f32_16x16x32_bf16(af, bq0, acc00, 0, 0, 0);
            acc01 = __builtin_amdgcn_mfma_f32_16x16x32_bf16(af, bq1, acc01, 0, 0, 0);
            acc02 = __builtin_amdgcn_mfma_f32_16x16x32_bf16(af, bq2, acc02, 0, 0, 0);
            acc03 = __builtin_amdgcn_mfma_f32_16x16x32_bf16(af, bq3, acc03, 0, 0, 0);
        }
        {   // m-tile 1
            const int rr = wave * 32 + 16 + m;
            const float4 xa = *(const float4*)&As[buf][rr * AST + q * 8];
            const float4 xb = *(const float4*)&As[buf][rr * AST + q * 8 + 4];
            short8 af;
            af[0] = (short)f2bf(xa.x); af[1] = (short)f2bf(xa.y);
            af[2] = (short)f2bf(xa.z); af[3] = (short)f2bf(xa.w);
            af[4] = (short)f2bf(xb.x); af[5] = (short)f2bf(xb.y);
            af[6] = (short)f2bf(xb.z); af[7] = (short)f2bf(xb.w);
            acc10 = __builtin_amdgcn_mfma_f32_16x16x32_bf16(af, bq0, acc10, 0, 0, 0);
            acc11 = __builtin_amdgcn_mfma_f32_16x16x32_bf16(af, bq1, acc11, 0, 0, 0);
            acc12 = __builtin_amdgcn_mfma_f32_16x16x32_bf16(af, bq2, acc12, 0, 0, 0);
            acc13 = __builtin_amdgcn_mfma_f32_16x16x32_bf16(af, bq3, acc13, 0, 0, 0);
        }

        if (havenext) {
            const int nb = buf ^ 1;
            *(float4*)&As[nb][(r0s +  0) * AST + c0s * 4] = pa0;
            *(float4*)&As[nb][(r0s + 32) * AST + c0s * 4] = pa1;
            *(float4*)&As[nb][(r0s + 64) * AST + c0s * 4] = pa2;
            *(float4*)&As[nb][(r0s + 96) * AST + c0s * 4] = pa3;
            *(short8*)&Bs[nb][bcol * BSTC + bkk] = pb;
        }
        __syncthreads();
        buf ^= 1;
    }

#pragma unroll
    for (int mt = 0; mt < 2; ++mt) {
        const f32x4 a0 = mt ? acc10 : acc00;
        const f32x4 a1 = mt ? acc11 : acc01;
        const f32x4 a2 = mt ? acc12 : acc02;
        const f32x4 a3 = mt ? acc13 : acc03;
        const int rb = row0 + wave * 32 + mt * 16 + q * 4;
#pragma unroll
        for (int nt = 0; nt < 4; ++nt) {
            const f32x4 av = (nt == 0) ? a0 : (nt == 1) ? a1 : (nt == 2) ? a2 : a3;
            const int col = nt * 16 + m;
            if (col < NLAB) {
                const float bv = bias[col];
#pragma unroll
                for (int r = 0; r < 4; ++r)
                    out[(size_t)(rb + r) * NLAB + col] = av[r] + bv;
            }
        }
    }
}

// ---------------------------------------------------------------------------
// CRF v8: v7 structure + amdgpu_waves_per_eu(1,1).
// Root cause of R1-R7 floor: default occupancy heuristic (8 waves/EU for a
// 512B-LDS kernel) capped the allocator at <=64 VGPRs (measured 40..60 every
// round), spilling et/emission state to scratch. Occupancy is irrelevant here
// (64 blocks x 1 wave on 256 CUs) -> pin waves/EU to 1, budget 512 VGPRs.
// ---------------------------------------------------------------------------
__device__ __forceinline__ float wave_sum(float v) {
#pragma unroll
    for (int off = 32; off > 0; off >>= 1) v += __shfl_xor(v, off, 64);
    return v;
}

#define ET_INIT(v, base)                            \
    v.x = __expf(trans[(base + 0) * NLAB + j]);     \
    v.y = __expf(trans[(base + 1) * NLAB + j]);     \
    v.z = __expf(trans[(base + 2) * NLAB + j]);     \
    v.w = __expf(trans[(base + 3) * NLAB + j]);

#define DOT4(idx, ee)                               \
    {                                               \
        const float4 v = *(const float4*)&eb[(idx) * 4]; \
        sa = fmaf(v.x, ee.x, sa);                   \
        sb = fmaf(v.y, ee.y, sb);                   \
        sc = fmaf(v.z, ee.z, sc);                   \
        sd = fmaf(v.w, ee.w, sd);                   \
    }

__global__ __launch_bounds__(64) __attribute__((amdgpu_waves_per_eu(1, 1)))
void crf_kernel(
    const float* __restrict__ logits,
    const int* __restrict__ labels,
    const void* __restrict__ maskp,
    const float* __restrict__ startT,
    const float* __restrict__ endT,
    const float* __restrict__ trans,
    float* __restrict__ llh) {
    const int b = blockIdx.x;
    const int lane = threadIdx.x;
    __shared__ __align__(16) float ea[2][64];

    // --- mask length (contiguous valid prefix) ---
    const int probe = ((const int*)maskp)[0];
    int len = 0;
    if (probe == 1) {
        const int* mk = (const int*)maskp + b * TLEN;
#pragma unroll
        for (int it = 0; it < 8; ++it)
            len += (int)__popcll(__ballot(mk[lane + it * 64] != 0));
    } else if (probe == 0x01010101) {
        const unsigned char* mk = (const unsigned char*)maskp + b * TLEN;
#pragma unroll
        for (int it = 0; it < 8; ++it)
            len += (int)__popcll(__ballot(mk[lane + it * 64] != 0));
    } else if (probe == 0x3F803F80) {
        const unsigned short* mk = (const unsigned short*)maskp + b * TLEN;
#pragma unroll
        for (int it = 0; it < 8; ++it)
            len += (int)__popcll(__ballot(mk[lane + it * 64] != 0));
    } else {
        const float* mk = (const float*)maskp + b * TLEN;
#pragma unroll
        for (int it = 0; it < 8; ++it)
            len += (int)__popcll(__ballot(mk[lane + it * 64] != 0.f));
    }

    const int j = lane;
    const int jc = (j < NLAB) ? j : (NLAB - 1);

    // et = exp(trans[:, j]) in 13 named float4 registers
    float4 et0  = {0.f,0.f,0.f,0.f}, et1  = {0.f,0.f,0.f,0.f};
    float4 et2  = {0.f,0.f,0.f,0.f}, et3  = {0.f,0.f,0.f,0.f};
    float4 et4  = {0.f,0.f,0.f,0.f}, et5  = {0.f,0.f,0.f,0.f};
    float4 et6  = {0.f,0.f,0.f,0.f}, et7  = {0.f,0.f,0.f,0.f};
    float4 et8  = {0.f,0.f,0.f,0.f}, et9  = {0.f,0.f,0.f,0.f};
    float4 et10 = {0.f,0.f,0.f,0.f}, et11 = {0.f,0.f,0.f,0.f};
    float4 et12 = {0.f,0.f,0.f,0.f};
    if (j < NLAB) {
        ET_INIT(et0,  0)  ET_INIT(et1,  4)  ET_INIT(et2,  8)
        ET_INIT(et3,  12) ET_INIT(et4,  16) ET_INIT(et5,  20)
        ET_INIT(et6,  24) ET_INIT(et7,  28) ET_INIT(et8,  32)
        ET_INIT(et9,  36) ET_INIT(et10, 40) ET_INIT(et11, 44)
        et12.x = __expf(trans[48 * NLAB + j]);
        et12.y = __expf(trans[49 * NLAB + j]);
    }

    const float* em = logits + (size_t)b * TLEN * NLAB;

    float a0v = (j < NLAB) ? (startT[j] + em[j]) : 0.f;
    const float Abc = __shfl(a0v, 0, 64);
    float e = (j < NLAB) ? __expf(a0v - Abc) : 0.f;
    float A = Abc;
    float v0cur = 1.0f;   // lane-0 raw value of current buffer (exp(0)=1)

    ea[0][lane] = e;
    wave_lds_fence();

    // 4-deep emission pipeline: named scalars, rotated by assignment.
    float q0 = em[1 * NLAB + jc];
    float q1 = em[2 * NLAB + jc];
    float q2 = em[3 * NLAB + jc];
    float q3 = em[4 * NLAB + jc];
    float pcur = __expf(q0);
    q0 = q1; q1 = q2; q2 = q3; q3 = em[5 * NLAB + jc];

    int buf = 0;
    for (int t = 1; t < len; ++t) {
        int tf = t + 5; tf = (tf < len) ? tf : (len - 1);
        const float newem = em[tf * NLAB + jc];      // issued, used 4 iters later
        const float pnext = __expf(q0);              // off-chain
        const float rv = __builtin_amdgcn_rcpf(v0cur);   // off-chain
        A += __logf(v0cur);                              // off-chain
        const float pr = pcur * rv;                      // off-chain

        const float* eb = ea[buf];
        float sa = 0.f, sb = 0.f, sc = 0.f, sd = 0.f;
        DOT4(0, et0)   DOT4(1, et1)   DOT4(2, et2)   DOT4(3, et3)
        DOT4(4, et4)   DOT4(5, et5)   DOT4(6, et6)   DOT4(7, et7)
        DOT4(8, et8)   DOT4(9, et9)   DOT4(10, et10) DOT4(11, et11)
        DOT4(12, et12)
        const float s = (sa + sb) + (sc + sd);
        const float u = s * pr;                      // raw (un-normalized)

        ea[buf ^ 1][lane] = u;
        wave_lds_fence();
        v0cur = readlane0(u);
        buf ^= 1;
        e = u;
        pcur = pnext; q0 = q1; q1 = q2; q2 = q3; q3 = newem;
    }

    // den = A + log( sum_j v_j * exp(end_j) )   [alpha_j = A + log v_j]
    const float wv = (j < NLAB) ? (e * __expf(endT[j])) : 0.f;
    const float den = A + __logf(wave_sum(wv));

    // numerator: gold path (contiguous mask -> parallel over t)
    const int* tg = labels + b * TLEN;
    float num = 0.f;
#pragma unroll
    for (int it = 0; it < 8; ++it) {
        const int t = lane + it * 64;
        if (t < len) {
            const int tag = tg[t];
            num += em[t * NLAB + tag];
            if (t >= 1) num += trans[tg[t - 1] * NLAB + tag];
        }
    }
    num = wave_sum(num);
    if (lane == 0) {
        num += startT[tg[0]] + endT[tg[len - 1]];
        llh[b] = num - den;
    }
}

__global__ __launch_bounds__(64) void loss_kernel(const float* __restrict__ llh,
                                                  float* __restrict__ out0) {
    float v = llh[threadIdx.x];
    v = wave_sum(v);
    if (threadIdx.x == 0) out0[0] = -(v * (1.0f / BATCH));
}

extern "C" void kernel_launch(void* const* d_in, const int* in_sizes, int n_in,
                              void* d_out, int out_size, void* d_ws, size_t ws_size,
                              hipStream_t stream) {
    (void)in_sizes; (void)n_in; (void)out_size; (void)ws_size;
    const float* emb    = (const float*)d_in[0];
    const int*   labels = (const int*)d_in[1];
    const void*  mask   = d_in[2];
    const float* W      = (const float*)d_in[3];
    const float* bias   = (const float*)d_in[4];
    const float* startT = (const float*)d_in[5];
    const float* endT   = (const float*)d_in[6];
    const float* trans  = (const float*)d_in[7];

    float* out    = (float*)d_out;
    float* logits = out + 1;
    float* llh    = (float*)d_ws;
    unsigned short* Bt = (unsigned short*)((char*)d_ws + 512);  // 96 KiB bf16 W^T

    wprep_kernel<<<(64 * DIM + 255) / 256, 256, 0, stream>>>(W, Bt);
    gemm_kernel<<<(BATCH * TLEN) / 128, 256, 0, stream>>>(emb, Bt, bias, logits);
    crf_kernel<<<BATCH, 64, 0, stream>>>(logits, labels, mask, startT, endT, trans, llh);
    loss_kernel<<<1, 64, 0, stream>>>(llh, out);
}